// Round 5
// baseline (301.038 us; speedup 1.0000x reference)
//
#include <hip/hip_runtime.h>

typedef short shortx8 __attribute__((ext_vector_type(8)));
typedef float floatx4 __attribute__((ext_vector_type(4)));
typedef unsigned short ushortx4 __attribute__((ext_vector_type(4)));
typedef unsigned short ushortx8 __attribute__((ext_vector_type(8)));

typedef __attribute__((address_space(1))) char gchar;
typedef __attribute__((address_space(3))) char lchar;

__device__ __forceinline__ void async16(const void* g, void* l) {
    __builtin_amdgcn_global_load_lds((gchar*)g, (lchar*)l, 16, 0, 0);
}

__device__ __forceinline__ unsigned short f2bf(float f) {
    union { float f; unsigned int u; } v;
    v.f = f;
    unsigned int r = v.u + 0x7fffu + ((v.u >> 16) & 1u);   // RNE
    return (unsigned short)(r >> 16);
}

__device__ __forceinline__ float bf2f(unsigned short h) {
    union { unsigned int u; float f; } v;
    v.u = ((unsigned int)h) << 16;
    return v.f;
}

// ---------------------------------------------------------------------------
// GEMM mainloop v2: C[256x128] += A[256xK] * B[128xK]^T (bf16, fp32 acc).
// 4 waves in 2x2; each wave owns a 128x64 quadrant = 8x4 fragments of
// 16x16x32 MFMA (32 MFMA per 12KB of LDS reads -> 375 B/MFMA vs 512 before).
// LDS: A = 16 groups x 1KB (16 rows each), B = 8 groups x 1KB.
// Chunk swizzle within a group: chunk(fr,kq) = fr*4 + (kq ^ ((fr>>1)&3)).
//  - staging (dest = base + lane*16): lane 4-lane-groups cover one 64B line
//    (kq permuted within the line) -> full coalescing;
//  - fragment read: within each 16-lane quarter-wave, all 8 bank-groups hit
//    exactly 2x -> conflict-free (2-way is free, m136).
// ---------------------------------------------------------------------------
__device__ __forceinline__ void gemm_mainloop(const ushort* __restrict__ Arow,
                                              const ushort* __restrict__ Brow,
                                              int K, ushort* As, ushort* Bs,
                                              floatx4 acc[8][4]) {
    const int t = threadIdx.x;
    const int w = t >> 6;
    const int lane = t & 63;
    const size_t ldb = (size_t)K * 2;      // row pitch in bytes
    const int frs = lane >> 2;             // staging row within 16-row group
    const int kqs = (lane & 3) ^ ((frs >> 1) & 3);
    const char* gA = (const char*)Arow + (size_t)(64 * w + frs) * ldb + (kqs << 4);
    const char* gB = (const char*)Brow + (size_t)(32 * w + frs) * ldb + (kqs << 4);
    char* lA = (char*)As + (4 * w) * 1024;   // wave stages A groups 4w..4w+3
    char* lB = (char*)Bs + (2 * w) * 1024;   // and B groups 2w..2w+1
    const int wm = w >> 1, wn = w & 1;
    const int fr = lane & 15, kq = lane >> 4;
    const int loff = fr * 64 + ((kq ^ ((fr >> 1) & 3)) << 4);
    const char* Afrag = (const char*)As + (8 * wm) * 1024 + loff;
    const char* Bfrag = (const char*)Bs + (4 * wn) * 1024 + loff;
    const int nk = K >> 5;
    for (int kt = 0; kt < nk; ++kt) {
        async16(gA,            lA);            // A rows 64w..64w+15
        async16(gA + 16 * ldb, lA + 1024);     // +16..31
        async16(gA + 32 * ldb, lA + 2048);     // +32..47
        async16(gA + 48 * ldb, lA + 3072);     // +48..63
        async16(gB,            lB);            // B rows 32w..32w+15
        async16(gB + 16 * ldb, lB + 1024);     // +16..31
        gA += 64;
        gB += 64;
        __syncthreads();
        shortx8 a[8], b[4];
#pragma unroll
        for (int i = 0; i < 8; ++i)
            a[i] = *(const shortx8*)(Afrag + i * 1024);
#pragma unroll
        for (int j = 0; j < 4; ++j)
            b[j] = *(const shortx8*)(Bfrag + j * 1024);
#pragma unroll
        for (int i = 0; i < 8; ++i)
#pragma unroll
            for (int j = 0; j < 4; ++j)
                acc[i][j] = __builtin_amdgcn_mfma_f32_16x16x32_bf16(a[i], b[j], acc[i][j], 0, 0, 0);
        __syncthreads();
    }
}

// ---------------------------------------------------------------------------
// QKV projection as ONE GEMM: M=8192, N=3072 (Wq|Wk|Wv rows), K=1024.
// Block tile 256x128; grid (24,32): 24 N-blocks share each 256-row x-tile.
// z = nglob>>10: z=0 Q (scaled 1/32,+bq), z=1 K (+bk), z=2 V transposed.
// ---------------------------------------------------------------------------
__global__ __launch_bounds__(256, 2)
void qkv_gemm(const ushort* __restrict__ xb, const ushort* __restrict__ Wb,
              const float* __restrict__ bq, const float* __restrict__ bk,
              const float* __restrict__ bv,
              ushort* __restrict__ Qs, ushort* __restrict__ Ks,
              ushort* __restrict__ Vt) {
    __shared__ __align__(16) ushort lds[12288];   // A 16KB | B 8KB
    const int mbase = blockIdx.y * 256;
    const int nglob = blockIdx.x * 128;
    const int z = nglob >> 10;          // uniform per block
    const int nbase = nglob & 1023;     // column within the z-th projection
    floatx4 acc[8][4];
    const floatx4 zero = {0.0f, 0.0f, 0.0f, 0.0f};
#pragma unroll
    for (int i = 0; i < 8; ++i)
#pragma unroll
        for (int j = 0; j < 4; ++j) acc[i][j] = zero;

    gemm_mainloop(xb + (size_t)mbase * 1024, Wb + (size_t)nglob * 1024,
                  1024, lds, lds + 8192, acc);

    const int t = threadIdx.x, w = t >> 6, lane = t & 63;
    const int wm = w >> 1, wn = w & 1;
    const int r0 = mbase + wm * 128 + (lane >> 4) * 4;
    const int c0 = nbase + wn * 64 + (lane & 15);
    const float* bias = (z == 0) ? bq : (z == 1) ? bk : bv;
    const float scale = (z == 0) ? 0.03125f : 1.0f;  // fold 1/sqrt(1024) into Q
    float bj[4];
#pragma unroll
    for (int j = 0; j < 4; ++j) bj[j] = bias[c0 + j * 16];

    if (z < 2) {
        ushort* O = (z == 0) ? Qs : Ks;
#pragma unroll
        for (int i = 0; i < 8; ++i)
#pragma unroll
            for (int j = 0; j < 4; ++j)
#pragma unroll
                for (int r = 0; r < 4; ++r) {
                    int gr = r0 + i * 16 + r;
                    int gc = c0 + j * 16;
                    O[(size_t)gr * 1024 + gc] = f2bf((acc[i][j][r] + bj[j]) * scale);
                }
    } else {
#pragma unroll
        for (int i = 0; i < 8; ++i)
#pragma unroll
            for (int j = 0; j < 4; ++j)
#pragma unroll
                for (int r = 0; r < 4; ++r) {
                    int gr = r0 + i * 16 + r;           // global row = b*2048 + s
                    int gc = c0 + j * 16;               // d
                    Vt[(size_t)(gr >> 11) * (1024 * 2048) + (size_t)gc * 2048 + (gr & 2047)] =
                        f2bf(acc[i][j][r] + bj[j]);
                }
    }
}

// ---------------------------------------------------------------------------
// Batched B^T GEMM, bf16 output (S = Q K^T). Block tile 256x128. grid.z=batch.
// ---------------------------------------------------------------------------
__global__ __launch_bounds__(256, 2)
void gemm_bt_bf16(const ushort* __restrict__ A, size_t sAz,
                  const ushort* __restrict__ B, size_t sBz,
                  ushort* __restrict__ C, size_t sCz, int N, int K) {
    __shared__ __align__(16) ushort lds[12288];
    const int mbase = blockIdx.y * 256;
    const int nbase = blockIdx.x * 128;
    const int z = blockIdx.z;
    floatx4 acc[8][4];
    const floatx4 zero = {0.0f, 0.0f, 0.0f, 0.0f};
#pragma unroll
    for (int i = 0; i < 8; ++i)
#pragma unroll
        for (int j = 0; j < 4; ++j) acc[i][j] = zero;

    gemm_mainloop(A + z * sAz + (size_t)mbase * K,
                  B + z * sBz + (size_t)nbase * K, K, lds, lds + 8192, acc);

    const int t = threadIdx.x, w = t >> 6, lane = t & 63;
    const int wm = w >> 1, wn = w & 1;
    const int r0 = mbase + wm * 128 + (lane >> 4) * 4;
    const int c0 = nbase + wn * 64 + (lane & 15);
    ushort* Cz = C + z * sCz;
#pragma unroll
    for (int i = 0; i < 8; ++i)
#pragma unroll
        for (int j = 0; j < 4; ++j)
#pragma unroll
            for (int r = 0; r < 4; ++r)
                Cz[(size_t)(r0 + i * 16 + r) * N + (c0 + j * 16)] = f2bf(acc[i][j][r]);
}

// ---------------------------------------------------------------------------
// Batched B^T GEMM, fp32 output (O = P Vt^T). Block tile 256x128. grid.z=batch.
// ---------------------------------------------------------------------------
__global__ __launch_bounds__(256, 2)
void gemm_bt_f32(const ushort* __restrict__ A, size_t sAz,
                 const ushort* __restrict__ B, size_t sBz,
                 float* __restrict__ C, size_t sCz, int N, int K) {
    __shared__ __align__(16) ushort lds[12288];
    const int mbase = blockIdx.y * 256;
    const int nbase = blockIdx.x * 128;
    const int z = blockIdx.z;
    floatx4 acc[8][4];
    const floatx4 zero = {0.0f, 0.0f, 0.0f, 0.0f};
#pragma unroll
    for (int i = 0; i < 8; ++i)
#pragma unroll
        for (int j = 0; j < 4; ++j) acc[i][j] = zero;

    gemm_mainloop(A + z * sAz + (size_t)mbase * K,
                  B + z * sBz + (size_t)nbase * K, K, lds, lds + 8192, acc);

    const int t = threadIdx.x, w = t >> 6, lane = t & 63;
    const int wm = w >> 1, wn = w & 1;
    const int r0 = mbase + wm * 128 + (lane >> 4) * 4;
    const int c0 = nbase + wn * 64 + (lane & 15);
    float* Cz = C + z * sCz;
#pragma unroll
    for (int i = 0; i < 8; ++i)
#pragma unroll
        for (int j = 0; j < 4; ++j)
#pragma unroll
            for (int r = 0; r < 4; ++r)
                Cz[(size_t)(r0 + i * 16 + r) * N + (c0 + j * 16)] = acc[i][j][r];
}

// ---------------------------------------------------------------------------
// In-place row softmax over 2048 bf16 logits. One block (256 thr) per row.
// ---------------------------------------------------------------------------
__global__ __launch_bounds__(256)
void softmax_rows_bf16(ushort* __restrict__ SP) {
    const int row = blockIdx.x;
    ushortx8* base = (ushortx8*)(SP + (size_t)row * 2048);
    const int t = threadIdx.x;
    const int w = t >> 6, lane = t & 63;
    ushortx8 v = base[t];
    float f[8];
#pragma unroll
    for (int k = 0; k < 8; ++k) f[k] = bf2f(v[k]);
    float m = f[0];
#pragma unroll
    for (int k = 1; k < 8; ++k) m = fmaxf(m, f[k]);
    for (int o = 32; o > 0; o >>= 1) m = fmaxf(m, __shfl_down(m, o));
    __shared__ float red[4];
    if (lane == 0) red[w] = m;
    __syncthreads();
    m = fmaxf(fmaxf(red[0], red[1]), fmaxf(red[2], red[3]));

    float e[8], s = 0.0f;
#pragma unroll
    for (int k = 0; k < 8; ++k) { e[k] = __expf(f[k] - m); s += e[k]; }
    for (int o = 32; o > 0; o >>= 1) s += __shfl_down(s, o);
    __syncthreads();
    if (lane == 0) red[w] = s;
    __syncthreads();
    float inv = 1.0f / (red[0] + red[1] + red[2] + red[3]);

    ushortx8 o;
#pragma unroll
    for (int k = 0; k < 8; ++k) o[k] = f2bf(e[k] * inv);
    base[t] = o;
}

// ---------------------------------------------------------------------------
// Merged fp32 -> bf16 cast for x | Wq | Wk | Wv (contiguous dst region).
// ---------------------------------------------------------------------------
__global__ __launch_bounds__(256)
void cast_bf16_all(const float* __restrict__ x, const float* __restrict__ Wq,
                   const float* __restrict__ Wk, const float* __restrict__ Wv,
                   ushort* __restrict__ dst) {
    const int NX = 2097152;   // 8192*1024/4
    const int NW = 262144;    // 1024*1024/4
    int i = blockIdx.x * 256 + threadIdx.x;
    const float* src;
    int off;
    if (i < NX)               { src = x;  off = 0; }
    else if (i < NX + NW)     { src = Wq; off = NX; }
    else if (i < NX + 2 * NW) { src = Wk; off = NX + NW; }
    else                      { src = Wv; off = NX + 2 * NW; }
    float4 v = ((const float4*)src)[i - off];
    ushortx4 o = {f2bf(v.x), f2bf(v.y), f2bf(v.z), f2bf(v.w)};
    ((ushortx4*)dst)[i] = o;
}

extern "C" void kernel_launch(void* const* d_in, const int* in_sizes, int n_in,
                              void* d_out, int out_size, void* d_ws, size_t ws_size,
                              hipStream_t stream) {
    const float* x  = (const float*)d_in[0];
    const float* bq = (const float*)d_in[2];
    const float* bk = (const float*)d_in[4];
    const float* bv = (const float*)d_in[6];
    float* out = (float*)d_out;

    const size_t R = 8192;   // B*S
    const size_t D = 1024;
    const size_t S = 2048;

    // ws layout (elems): xb R*D | Wb 3*D*D | Qs R*D | Ks R*D | Vt R*D | Sb 4*S*S(bf16)
    const size_t need = (4 * R * D + 3 * D * D + 4 * S * S) * 2;
    if (ws_size < need) return;

    ushort* xb = (ushort*)d_ws;
    ushort* Wb = xb + R * D;
    ushort* Qs = Wb + 3 * D * D;
    ushort* Ks = Qs + R * D;
    ushort* Vt = Ks + R * D;
    ushort* Sb = Vt + R * D;   // S scores, then P in place (bf16)

    cast_bf16_all<<<dim3(11264), dim3(256), 0, stream>>>(
        x, (const float*)d_in[1], (const float*)d_in[3], (const float*)d_in[5], xb);

    // QKV: one GEMM M=8192 N=3072 K=1024, block tile 256x128
    qkv_gemm<<<dim3(24, 32), dim3(256), 0, stream>>>(xb, Wb, bq, bk, bv, Qs, Ks, Vt);

    // S = Qs @ K^T per batch: M=N=2048, K=1024 (scale folded into Qs), bf16 out
    gemm_bt_bf16<<<dim3(16, 8, 4), dim3(256), 0, stream>>>(Qs, S * D, Ks, S * D, Sb, S * S,
                                                           (int)S, (int)D);

    // softmax rows in place -> bf16 P
    softmax_rows_bf16<<<dim3((unsigned)(4 * S)), dim3(256), 0, stream>>>(Sb);

    // O = P @ Vt^T per batch: M=2048, N=1024, K=2048
    gemm_bt_f32<<<dim3(8, 8, 4), dim3(256), 0, stream>>>(Sb, S * S, Vt, D * S, out, S * D,
                                                         (int)D, (int)S);
}

// Round 6
// 273.667 us; speedup vs baseline: 1.1000x; 1.1000x over previous
//
#include <hip/hip_runtime.h>

typedef short shortx8 __attribute__((ext_vector_type(8)));
typedef float floatx4 __attribute__((ext_vector_type(4)));
typedef unsigned short ushortx4 __attribute__((ext_vector_type(4)));
typedef unsigned short ushortx8 __attribute__((ext_vector_type(8)));

typedef __attribute__((address_space(1))) char gchar;
typedef __attribute__((address_space(3))) char lchar;

__device__ __forceinline__ void async16(const void* g, void* l) {
    __builtin_amdgcn_global_load_lds((gchar*)g, (lchar*)l, 16, 0, 0);
}

__device__ __forceinline__ unsigned short f2bf(float f) {
    union { float f; unsigned int u; } v;
    v.f = f;
    unsigned int r = v.u + 0x7fffu + ((v.u >> 16) & 1u);   // RNE
    return (unsigned short)(r >> 16);
}

__device__ __forceinline__ float bf2f(unsigned short h) {
    union { unsigned int u; float f; } v;
    v.u = ((unsigned int)h) << 16;
    return v.f;
}

// ---------------------------------------------------------------------------
// GEMM mainloop: C[128x128] += A[128xK] * B[128xK]^T (bf16, fp32 acc).
// 128x128 block tile, 4 waves in 2x2 (64x64 each), 16x16x32 MFMA, BK=32.
// LDS: A,B = 8 groups x 1KB (16 rows each).
// Chunk swizzle within a group: chunk(fr,kq) = fr*4 + (kq ^ ((fr>>1)&3)).
//  - staging (dest = base + lane*16): each 4-lane group covers ONE 64B row
//    segment (kq permuted within the line) -> full coalescing;
//  - fragment read: within each 16-lane quarter-wave all 8 bank-groups are
//    hit exactly 2x -> conflict-free (2-way is free; verified R5: 0 conflicts).
// 3 blocks/CU via __launch_bounds__(256,3): barrier-latency hiding needs >=3
// resident blocks (R5 showed 1 block/CU doubles per-iter time).
// ---------------------------------------------------------------------------
__device__ __forceinline__ void gemm_mainloop(const ushort* __restrict__ Arow,
                                              const ushort* __restrict__ Brow,
                                              int K, ushort* As, ushort* Bs,
                                              floatx4 acc[4][4]) {
    const int t = threadIdx.x;
    const int w = t >> 6;
    const int lane = t & 63;
    const size_t ldb = (size_t)K * 2;      // row pitch in bytes
    const int frs = lane >> 2;             // staging row within 16-row group
    const int kqs = (lane & 3) ^ ((frs >> 1) & 3);
    const char* gA = (const char*)Arow + (size_t)(16 * w + frs) * ldb + (kqs << 4);
    const char* gB = (const char*)Brow + (size_t)(16 * w + frs) * ldb + (kqs << 4);
    char* lA = (char*)As + w * 1024;       // wave stages A group w (+4 for rows 64+)
    char* lB = (char*)Bs + w * 1024;
    const int ga0 = (w & 1) * 4;           // A fragment group base
    const int gb0 = (w >> 1) * 4;          // B fragment group base
    const int fr = lane & 15, kq = lane >> 4;
    const int loff = fr * 64 + ((kq ^ ((fr >> 1) & 3)) << 4);
    const char* Afrag = (const char*)As + ga0 * 1024 + loff;
    const char* Bfrag = (const char*)Bs + gb0 * 1024 + loff;
    const int nk = K >> 5;
    for (int kt = 0; kt < nk; ++kt) {
        async16(gA,            lA);            // A rows 16w..16w+15  (groups 0-3)
        async16(gA + 64 * ldb, lA + 4096);     // rows 64+16w..+15    (groups 4-7)
        async16(gB,            lB);
        async16(gB + 64 * ldb, lB + 4096);
        gA += 64;
        gB += 64;
        __syncthreads();
        shortx8 a[4], b[4];
#pragma unroll
        for (int i = 0; i < 4; ++i)
            a[i] = *(const shortx8*)(Afrag + i * 1024);
#pragma unroll
        for (int j = 0; j < 4; ++j)
            b[j] = *(const shortx8*)(Bfrag + j * 1024);
#pragma unroll
        for (int i = 0; i < 4; ++i)
#pragma unroll
            for (int j = 0; j < 4; ++j)
                acc[i][j] = __builtin_amdgcn_mfma_f32_16x16x32_bf16(a[i], b[j], acc[i][j], 0, 0, 0);
        __syncthreads();
    }
}

// ---------------------------------------------------------------------------
// QKV projection as ONE GEMM: M=8192, N=3072 (Wq|Wk|Wv rows), K=1024.
// grid (24,64): 24 N-blocks share each 128-row x-tile -> L2 reuse.
// z = nglob>>10: z=0 Q (scaled 1/32,+bq), z=1 K (+bk), z=2 V transposed.
// ---------------------------------------------------------------------------
__global__ __launch_bounds__(256, 3)
void qkv_gemm(const ushort* __restrict__ xb, const ushort* __restrict__ Wb,
              const float* __restrict__ bq, const float* __restrict__ bk,
              const float* __restrict__ bv,
              ushort* __restrict__ Qs, ushort* __restrict__ Ks,
              ushort* __restrict__ Vt) {
    __shared__ __align__(16) ushort lds[8192];
    const int mbase = blockIdx.y * 128;
    const int nglob = blockIdx.x * 128;
    const int z = nglob >> 10;          // uniform per block
    const int nbase = nglob & 1023;     // column within the z-th projection
    floatx4 acc[4][4];
    const floatx4 zero = {0.0f, 0.0f, 0.0f, 0.0f};
#pragma unroll
    for (int i = 0; i < 4; ++i)
#pragma unroll
        for (int j = 0; j < 4; ++j) acc[i][j] = zero;

    gemm_mainloop(xb + (size_t)mbase * 1024, Wb + (size_t)nglob * 1024,
                  1024, lds, lds + 4096, acc);

    const int t = threadIdx.x, w = t >> 6, lane = t & 63;
    const int mw = (w & 1) * 64, nw = (w >> 1) * 64;
    const int r0 = mbase + mw + (lane >> 4) * 4;
    const int c0 = nbase + nw + (lane & 15);
    const float* bias = (z == 0) ? bq : (z == 1) ? bk : bv;
    const float scale = (z == 0) ? 0.03125f : 1.0f;  // fold 1/sqrt(1024) into Q
    float bj[4];
#pragma unroll
    for (int j = 0; j < 4; ++j) bj[j] = bias[c0 + j * 16];

    if (z < 2) {
        ushort* O = (z == 0) ? Qs : Ks;
#pragma unroll
        for (int i = 0; i < 4; ++i)
#pragma unroll
            for (int j = 0; j < 4; ++j)
#pragma unroll
                for (int r = 0; r < 4; ++r) {
                    int gr = r0 + i * 16 + r;
                    int gc = c0 + j * 16;
                    O[(size_t)gr * 1024 + gc] = f2bf((acc[i][j][r] + bj[j]) * scale);
                }
    } else {
#pragma unroll
        for (int i = 0; i < 4; ++i)
#pragma unroll
            for (int j = 0; j < 4; ++j)
#pragma unroll
                for (int r = 0; r < 4; ++r) {
                    int gr = r0 + i * 16 + r;           // global row = b*2048 + s
                    int gc = c0 + j * 16;               // d
                    Vt[(size_t)(gr >> 11) * (1024 * 2048) + (size_t)gc * 2048 + (gr & 2047)] =
                        f2bf(acc[i][j][r] + bj[j]);
                }
    }
}

// ---------------------------------------------------------------------------
// Batched B^T GEMM, bf16 output (S = Q K^T). grid.z = batch.
// ---------------------------------------------------------------------------
__global__ __launch_bounds__(256, 3)
void gemm_bt_bf16(const ushort* __restrict__ A, size_t sAz,
                  const ushort* __restrict__ B, size_t sBz,
                  ushort* __restrict__ C, size_t sCz, int N, int K) {
    __shared__ __align__(16) ushort lds[8192];
    const int mbase = blockIdx.y * 128;
    const int nbase = blockIdx.x * 128;
    const int z = blockIdx.z;
    floatx4 acc[4][4];
    const floatx4 zero = {0.0f, 0.0f, 0.0f, 0.0f};
#pragma unroll
    for (int i = 0; i < 4; ++i)
#pragma unroll
        for (int j = 0; j < 4; ++j) acc[i][j] = zero;

    gemm_mainloop(A + z * sAz + (size_t)mbase * K,
                  B + z * sBz + (size_t)nbase * K, K, lds, lds + 4096, acc);

    const int t = threadIdx.x, w = t >> 6, lane = t & 63;
    const int mw = (w & 1) * 64, nw = (w >> 1) * 64;
    const int r0 = mbase + mw + (lane >> 4) * 4;
    const int c0 = nbase + nw + (lane & 15);
    ushort* Cz = C + z * sCz;
#pragma unroll
    for (int i = 0; i < 4; ++i)
#pragma unroll
        for (int j = 0; j < 4; ++j)
#pragma unroll
            for (int r = 0; r < 4; ++r)
                Cz[(size_t)(r0 + i * 16 + r) * N + (c0 + j * 16)] = f2bf(acc[i][j][r]);
}

// ---------------------------------------------------------------------------
// Batched B^T GEMM, fp32 output (O = P Vt^T). grid.z = batch.
// ---------------------------------------------------------------------------
__global__ __launch_bounds__(256, 3)
void gemm_bt_f32(const ushort* __restrict__ A, size_t sAz,
                 const ushort* __restrict__ B, size_t sBz,
                 float* __restrict__ C, size_t sCz, int N, int K) {
    __shared__ __align__(16) ushort lds[8192];
    const int mbase = blockIdx.y * 128;
    const int nbase = blockIdx.x * 128;
    const int z = blockIdx.z;
    floatx4 acc[4][4];
    const floatx4 zero = {0.0f, 0.0f, 0.0f, 0.0f};
#pragma unroll
    for (int i = 0; i < 4; ++i)
#pragma unroll
        for (int j = 0; j < 4; ++j) acc[i][j] = zero;

    gemm_mainloop(A + z * sAz + (size_t)mbase * K,
                  B + z * sBz + (size_t)nbase * K, K, lds, lds + 4096, acc);

    const int t = threadIdx.x, w = t >> 6, lane = t & 63;
    const int mw = (w & 1) * 64, nw = (w >> 1) * 64;
    const int r0 = mbase + mw + (lane >> 4) * 4;
    const int c0 = nbase + nw + (lane & 15);
    float* Cz = C + z * sCz;
#pragma unroll
    for (int i = 0; i < 4; ++i)
#pragma unroll
        for (int j = 0; j < 4; ++j)
#pragma unroll
            for (int r = 0; r < 4; ++r)
                Cz[(size_t)(r0 + i * 16 + r) * N + (c0 + j * 16)] = acc[i][j][r];
}

// ---------------------------------------------------------------------------
// In-place row softmax over 2048 bf16 logits. One block (256 thr) per row.
// ---------------------------------------------------------------------------
__global__ __launch_bounds__(256)
void softmax_rows_bf16(ushort* __restrict__ SP) {
    const int row = blockIdx.x;
    ushortx8* base = (ushortx8*)(SP + (size_t)row * 2048);
    const int t = threadIdx.x;
    const int w = t >> 6, lane = t & 63;
    ushortx8 v = base[t];
    float f[8];
#pragma unroll
    for (int k = 0; k < 8; ++k) f[k] = bf2f(v[k]);
    float m = f[0];
#pragma unroll
    for (int k = 1; k < 8; ++k) m = fmaxf(m, f[k]);
    for (int o = 32; o > 0; o >>= 1) m = fmaxf(m, __shfl_down(m, o));
    __shared__ float red[4];
    if (lane == 0) red[w] = m;
    __syncthreads();
    m = fmaxf(fmaxf(red[0], red[1]), fmaxf(red[2], red[3]));

    float e[8], s = 0.0f;
#pragma unroll
    for (int k = 0; k < 8; ++k) { e[k] = __expf(f[k] - m); s += e[k]; }
    for (int o = 32; o > 0; o >>= 1) s += __shfl_down(s, o);
    __syncthreads();
    if (lane == 0) red[w] = s;
    __syncthreads();
    float inv = 1.0f / (red[0] + red[1] + red[2] + red[3]);

    ushortx8 o;
#pragma unroll
    for (int k = 0; k < 8; ++k) o[k] = f2bf(e[k] * inv);
    base[t] = o;
}

// ---------------------------------------------------------------------------
// Merged fp32 -> bf16 cast for x | Wq | Wk | Wv (contiguous dst region).
// ---------------------------------------------------------------------------
__global__ __launch_bounds__(256)
void cast_bf16_all(const float* __restrict__ x, const float* __restrict__ Wq,
                   const float* __restrict__ Wk, const float* __restrict__ Wv,
                   ushort* __restrict__ dst) {
    const int NX = 2097152;   // 8192*1024/4
    const int NW = 262144;    // 1024*1024/4
    int i = blockIdx.x * 256 + threadIdx.x;
    const float* src;
    int off;
    if (i < NX)               { src = x;  off = 0; }
    else if (i < NX + NW)     { src = Wq; off = NX; }
    else if (i < NX + 2 * NW) { src = Wk; off = NX + NW; }
    else                      { src = Wv; off = NX + 2 * NW; }
    float4 v = ((const float4*)src)[i - off];
    ushortx4 o = {f2bf(v.x), f2bf(v.y), f2bf(v.z), f2bf(v.w)};
    ((ushortx4*)dst)[i] = o;
}

extern "C" void kernel_launch(void* const* d_in, const int* in_sizes, int n_in,
                              void* d_out, int out_size, void* d_ws, size_t ws_size,
                              hipStream_t stream) {
    const float* x  = (const float*)d_in[0];
    const float* bq = (const float*)d_in[2];
    const float* bk = (const float*)d_in[4];
    const float* bv = (const float*)d_in[6];
    float* out = (float*)d_out;

    const size_t R = 8192;   // B*S
    const size_t D = 1024;
    const size_t S = 2048;

    // ws layout (elems): xb R*D | Wb 3*D*D | Qs R*D | Ks R*D | Vt R*D | Sb 4*S*S(bf16)
    const size_t need = (4 * R * D + 3 * D * D + 4 * S * S) * 2;
    if (ws_size < need) return;

    ushort* xb = (ushort*)d_ws;
    ushort* Wb = xb + R * D;
    ushort* Qs = Wb + 3 * D * D;
    ushort* Ks = Qs + R * D;
    ushort* Vt = Ks + R * D;
    ushort* Sb = Vt + R * D;   // S scores, then P in place (bf16)

    cast_bf16_all<<<dim3(11264), dim3(256), 0, stream>>>(
        x, (const float*)d_in[1], (const float*)d_in[3], (const float*)d_in[5], xb);

    // QKV: one GEMM M=8192 N=3072 K=1024; 24 N-blocks share each x-tile
    qkv_gemm<<<dim3(24, 64), dim3(256), 0, stream>>>(xb, Wb, bq, bk, bv, Qs, Ks, Vt);

    // S = Qs @ K^T per batch: M=N=2048, K=1024 (scale folded into Qs), bf16 out
    gemm_bt_bf16<<<dim3(16, 16, 4), dim3(256), 0, stream>>>(Qs, S * D, Ks, S * D, Sb, S * S,
                                                            (int)S, (int)D);

    // softmax rows in place -> bf16 P
    softmax_rows_bf16<<<dim3((unsigned)(4 * S)), dim3(256), 0, stream>>>(Sb);

    // O = P @ Vt^T per batch: M=2048, N=1024, K=2048
    gemm_bt_f32<<<dim3(8, 16, 4), dim3(256), 0, stream>>>(Sb, S * S, Vt, D * S, out, S * D,
                                                          (int)D, (int)S);
}

// Round 8
// 249.036 us; speedup vs baseline: 1.2088x; 1.0989x over previous
//
#include <hip/hip_runtime.h>

typedef short shortx8 __attribute__((ext_vector_type(8)));
typedef float floatx4 __attribute__((ext_vector_type(4)));
typedef unsigned short ushortx4 __attribute__((ext_vector_type(4)));
typedef unsigned short ushortx8 __attribute__((ext_vector_type(8)));

typedef __attribute__((address_space(1))) char gchar;
typedef __attribute__((address_space(3))) char lchar;

__device__ __forceinline__ void async16(const void* g, void* l) {
    __builtin_amdgcn_global_load_lds((gchar*)g, (lchar*)l, 16, 0, 0);
}

__device__ __forceinline__ unsigned short f2bf(float f) {
    union { float f; unsigned int u; } v;
    v.f = f;
    unsigned int r = v.u + 0x7fffu + ((v.u >> 16) & 1u);   // RNE
    return (unsigned short)(r >> 16);
}

__device__ __forceinline__ float bf2f(unsigned short h) {
    union { unsigned int u; float f; } v;
    v.u = ((unsigned int)h) << 16;
    return v.f;
}

// ---------------------------------------------------------------------------
// GEMM mainloop, BK=64: C[128x128] += A[128xK] * B[128xK]^T (bf16, fp32 acc).
// Per-iteration latency amortization: two k=32 sub-steps per staged tile.
// LDS layout per tile: 8 groups x 2KB; group g = rows 16g..16g+15, row fr's
// chunk position p holds data chunk p ^ xr(fr), xr(fr) = (fr>>1)&7.
// Staging (dest = base + lane*16): slabs covering rows 0..7 of a group use
// column (lane&7)^(lane>>4); rows 8..15 use the same ^4 (xr = 4+(lane>>4)).
// [R7 bug: one column for all slabs -> rows 8..15 XOR-4 misplaced. Fixed.]
//  - each 8-lane group covers ONE contiguous 128B row segment -> coalesced;
//  - fragment reads: per quarter-wave every bank-group hit exactly 2x -> free.
// ---------------------------------------------------------------------------
__device__ __forceinline__ void gemm_mainloop(const ushort* __restrict__ Arow,
                                              const ushort* __restrict__ Brow,
                                              int K, ushort* As, ushort* Bs,
                                              floatx4 acc[4][4]) {
    const int t = threadIdx.x;
    const int w = t >> 6;
    const int lane = t & 63;
    const size_t ldb = (size_t)K * 2;      // row pitch in bytes
    const int frs = lane >> 3;             // staging row 0..7 within 8-row slab
    const int kql = (lane & 7) ^ (lane >> 4);   // column for rows 0..7 of group
    const char* gA0 = (const char*)Arow + (size_t)(32 * w + frs) * ldb + (kql << 4);
    const char* gA1 = (const char*)Arow + (size_t)(32 * w + 8 + frs) * ldb + ((kql ^ 4) << 4);
    const char* gB0 = (const char*)Brow + (size_t)(32 * w + frs) * ldb + (kql << 4);
    const char* gB1 = (const char*)Brow + (size_t)(32 * w + 8 + frs) * ldb + ((kql ^ 4) << 4);
    char* lA = (char*)As + w * 4096;       // wave w stages rows 32w..32w+31
    char* lB = (char*)Bs + w * 4096;
    const int ga0 = (w & 1) * 4;           // A fragment group base
    const int gb0 = (w >> 1) * 4;          // B fragment group base
    const int fr = lane & 15;
    const int kq = lane >> 4;              // 0..3
    const int xr = (fr >> 1) & 7;
    const int loff0 = fr * 128 + ((kq ^ xr) << 4);         // sub-k 0 (k 0..31)
    const int loff1 = fr * 128 + (((kq + 4) ^ xr) << 4);   // sub-k 1 (k 32..63)
    const int nk = K >> 6;
    for (int kt = 0; kt < nk; ++kt) {
        async16(gA0,            lA);            // group 2w,   rows 0..7
        async16(gA1,            lA + 1024);     // group 2w,   rows 8..15
        async16(gA0 + 16 * ldb, lA + 2048);     // group 2w+1, rows 0..7
        async16(gA1 + 16 * ldb, lA + 3072);     // group 2w+1, rows 8..15
        async16(gB0,            lB);
        async16(gB1,            lB + 1024);
        async16(gB0 + 16 * ldb, lB + 2048);
        async16(gB1 + 16 * ldb, lB + 3072);
        gA0 += 128; gA1 += 128; gB0 += 128; gB1 += 128;
        __syncthreads();
        shortx8 a0[4], b0[4], a1[4], b1[4];
#pragma unroll
        for (int i = 0; i < 4; ++i) {
            a0[i] = *(const shortx8*)((const char*)As + (ga0 + i) * 2048 + loff0);
            a1[i] = *(const shortx8*)((const char*)As + (ga0 + i) * 2048 + loff1);
        }
#pragma unroll
        for (int j = 0; j < 4; ++j) {
            b0[j] = *(const shortx8*)((const char*)Bs + (gb0 + j) * 2048 + loff0);
            b1[j] = *(const shortx8*)((const char*)Bs + (gb0 + j) * 2048 + loff1);
        }
#pragma unroll
        for (int i = 0; i < 4; ++i)
#pragma unroll
            for (int j = 0; j < 4; ++j)
                acc[i][j] = __builtin_amdgcn_mfma_f32_16x16x32_bf16(a0[i], b0[j], acc[i][j], 0, 0, 0);
#pragma unroll
        for (int i = 0; i < 4; ++i)
#pragma unroll
            for (int j = 0; j < 4; ++j)
                acc[i][j] = __builtin_amdgcn_mfma_f32_16x16x32_bf16(a1[i], b1[j], acc[i][j], 0, 0, 0);
        __syncthreads();
    }
}

// ---------------------------------------------------------------------------
// QKV projection as ONE GEMM: M=8192, N=3072 (Wq|Wk|Wv rows), K=1024.
// grid (24,64): 24 N-blocks share each 128-row x-tile -> L2 reuse.
// z = nglob>>10: z=0 Q (scaled 1/32,+bq), z=1 K (+bk), z=2 V transposed.
// ---------------------------------------------------------------------------
__global__ __launch_bounds__(256, 3)
void qkv_gemm(const ushort* __restrict__ xb, const ushort* __restrict__ Wb,
              const float* __restrict__ bq, const float* __restrict__ bk,
              const float* __restrict__ bv,
              ushort* __restrict__ Qs, ushort* __restrict__ Ks,
              ushort* __restrict__ Vt) {
    __shared__ __align__(16) ushort lds[16384];   // A 16KB | B 16KB
    const int mbase = blockIdx.y * 128;
    const int nglob = blockIdx.x * 128;
    const int z = nglob >> 10;          // uniform per block
    const int nbase = nglob & 1023;     // column within the z-th projection
    floatx4 acc[4][4];
    const floatx4 zero = {0.0f, 0.0f, 0.0f, 0.0f};
#pragma unroll
    for (int i = 0; i < 4; ++i)
#pragma unroll
        for (int j = 0; j < 4; ++j) acc[i][j] = zero;

    gemm_mainloop(xb + (size_t)mbase * 1024, Wb + (size_t)nglob * 1024,
                  1024, lds, lds + 8192, acc);

    const int t = threadIdx.x, w = t >> 6, lane = t & 63;
    const int mw = (w & 1) * 64, nw = (w >> 1) * 64;
    const int r0 = mbase + mw + (lane >> 4) * 4;
    const int c0 = nbase + nw + (lane & 15);
    const float* bias = (z == 0) ? bq : (z == 1) ? bk : bv;
    const float scale = (z == 0) ? 0.03125f : 1.0f;  // fold 1/sqrt(1024) into Q
    float bj[4];
#pragma unroll
    for (int j = 0; j < 4; ++j) bj[j] = bias[c0 + j * 16];

    if (z < 2) {
        ushort* O = (z == 0) ? Qs : Ks;
#pragma unroll
        for (int i = 0; i < 4; ++i)
#pragma unroll
            for (int j = 0; j < 4; ++j)
#pragma unroll
                for (int r = 0; r < 4; ++r) {
                    int gr = r0 + i * 16 + r;
                    int gc = c0 + j * 16;
                    O[(size_t)gr * 1024 + gc] = f2bf((acc[i][j][r] + bj[j]) * scale);
                }
    } else {
#pragma unroll
        for (int i = 0; i < 4; ++i)
#pragma unroll
            for (int j = 0; j < 4; ++j)
#pragma unroll
                for (int r = 0; r < 4; ++r) {
                    int gr = r0 + i * 16 + r;           // global row = b*2048 + s
                    int gc = c0 + j * 16;               // d
                    Vt[(size_t)(gr >> 11) * (1024 * 2048) + (size_t)gc * 2048 + (gr & 2047)] =
                        f2bf(acc[i][j][r] + bj[j]);
                }
    }
}

// ---------------------------------------------------------------------------
// Batched B^T GEMM, bf16 output (S = Q K^T). grid.z = batch.
// ---------------------------------------------------------------------------
__global__ __launch_bounds__(256, 3)
void gemm_bt_bf16(const ushort* __restrict__ A, size_t sAz,
                  const ushort* __restrict__ B, size_t sBz,
                  ushort* __restrict__ C, size_t sCz, int N, int K) {
    __shared__ __align__(16) ushort lds[16384];
    const int mbase = blockIdx.y * 128;
    const int nbase = blockIdx.x * 128;
    const int z = blockIdx.z;
    floatx4 acc[4][4];
    const floatx4 zero = {0.0f, 0.0f, 0.0f, 0.0f};
#pragma unroll
    for (int i = 0; i < 4; ++i)
#pragma unroll
        for (int j = 0; j < 4; ++j) acc[i][j] = zero;

    gemm_mainloop(A + z * sAz + (size_t)mbase * K,
                  B + z * sBz + (size_t)nbase * K, K, lds, lds + 8192, acc);

    const int t = threadIdx.x, w = t >> 6, lane = t & 63;
    const int mw = (w & 1) * 64, nw = (w >> 1) * 64;
    const int r0 = mbase + mw + (lane >> 4) * 4;
    const int c0 = nbase + nw + (lane & 15);
    ushort* Cz = C + z * sCz;
#pragma unroll
    for (int i = 0; i < 4; ++i)
#pragma unroll
        for (int j = 0; j < 4; ++j)
#pragma unroll
            for (int r = 0; r < 4; ++r)
                Cz[(size_t)(r0 + i * 16 + r) * N + (c0 + j * 16)] = f2bf(acc[i][j][r]);
}

// ---------------------------------------------------------------------------
// Batched B^T GEMM, fp32 output (O = P Vt^T). grid.z = batch.
// ---------------------------------------------------------------------------
__global__ __launch_bounds__(256, 3)
void gemm_bt_f32(const ushort* __restrict__ A, size_t sAz,
                 const ushort* __restrict__ B, size_t sBz,
                 float* __restrict__ C, size_t sCz, int N, int K) {
    __shared__ __align__(16) ushort lds[16384];
    const int mbase = blockIdx.y * 128;
    const int nbase = blockIdx.x * 128;
    const int z = blockIdx.z;
    floatx4 acc[4][4];
    const floatx4 zero = {0.0f, 0.0f, 0.0f, 0.0f};
#pragma unroll
    for (int i = 0; i < 4; ++i)
#pragma unroll
        for (int j = 0; j < 4; ++j) acc[i][j] = zero;

    gemm_mainloop(A + z * sAz + (size_t)mbase * K,
                  B + z * sBz + (size_t)nbase * K, K, lds, lds + 8192, acc);

    const int t = threadIdx.x, w = t >> 6, lane = t & 63;
    const int mw = (w & 1) * 64, nw = (w >> 1) * 64;
    const int r0 = mbase + mw + (lane >> 4) * 4;
    const int c0 = nbase + nw + (lane & 15);
    float* Cz = C + z * sCz;
#pragma unroll
    for (int i = 0; i < 4; ++i)
#pragma unroll
        for (int j = 0; j < 4; ++j)
#pragma unroll
            for (int r = 0; r < 4; ++r)
                Cz[(size_t)(r0 + i * 16 + r) * N + (c0 + j * 16)] = acc[i][j][r];
}

// ---------------------------------------------------------------------------
// In-place row softmax over 2048 bf16 logits. One block (256 thr) per row.
// ---------------------------------------------------------------------------
__global__ __launch_bounds__(256)
void softmax_rows_bf16(ushort* __restrict__ SP) {
    const int row = blockIdx.x;
    ushortx8* base = (ushortx8*)(SP + (size_t)row * 2048);
    const int t = threadIdx.x;
    const int w = t >> 6, lane = t & 63;
    ushortx8 v = base[t];
    float f[8];
#pragma unroll
    for (int k = 0; k < 8; ++k) f[k] = bf2f(v[k]);
    float m = f[0];
#pragma unroll
    for (int k = 1; k < 8; ++k) m = fmaxf(m, f[k]);
    for (int o = 32; o > 0; o >>= 1) m = fmaxf(m, __shfl_down(m, o));
    __shared__ float red[4];
    if (lane == 0) red[w] = m;
    __syncthreads();
    m = fmaxf(fmaxf(red[0], red[1]), fmaxf(red[2], red[3]));

    float e[8], s = 0.0f;
#pragma unroll
    for (int k = 0; k < 8; ++k) { e[k] = __expf(f[k] - m); s += e[k]; }
    for (int o = 32; o > 0; o >>= 1) s += __shfl_down(s, o);
    __syncthreads();
    if (lane == 0) red[w] = s;
    __syncthreads();
    float inv = 1.0f / (red[0] + red[1] + red[2] + red[3]);

    ushortx8 o;
#pragma unroll
    for (int k = 0; k < 8; ++k) o[k] = f2bf(e[k] * inv);
    base[t] = o;
}

// ---------------------------------------------------------------------------
// Merged fp32 -> bf16 cast for x | Wq | Wk | Wv (contiguous dst region).
// ---------------------------------------------------------------------------
__global__ __launch_bounds__(256)
void cast_bf16_all(const float* __restrict__ x, const float* __restrict__ Wq,
                   const float* __restrict__ Wk, const float* __restrict__ Wv,
                   ushort* __restrict__ dst) {
    const int NX = 2097152;   // 8192*1024/4
    const int NW = 262144;    // 1024*1024/4
    int i = blockIdx.x * 256 + threadIdx.x;
    const float* src;
    int off;
    if (i < NX)               { src = x;  off = 0; }
    else if (i < NX + NW)     { src = Wq; off = NX; }
    else if (i < NX + 2 * NW) { src = Wk; off = NX + NW; }
    else                      { src = Wv; off = NX + 2 * NW; }
    float4 v = ((const float4*)src)[i - off];
    ushortx4 o = {f2bf(v.x), f2bf(v.y), f2bf(v.z), f2bf(v.w)};
    ((ushortx4*)dst)[i] = o;
}

extern "C" void kernel_launch(void* const* d_in, const int* in_sizes, int n_in,
                              void* d_out, int out_size, void* d_ws, size_t ws_size,
                              hipStream_t stream) {
    const float* x  = (const float*)d_in[0];
    const float* bq = (const float*)d_in[2];
    const float* bk = (const float*)d_in[4];
    const float* bv = (const float*)d_in[6];
    float* out = (float*)d_out;

    const size_t R = 8192;   // B*S
    const size_t D = 1024;
    const size_t S = 2048;

    // ws layout (elems): xb R*D | Wb 3*D*D | Qs R*D | Ks R*D | Vt R*D | Sb 4*S*S(bf16)
    const size_t need = (4 * R * D + 3 * D * D + 4 * S * S) * 2;
    if (ws_size < need) return;

    ushort* xb = (ushort*)d_ws;
    ushort* Wb = xb + R * D;
    ushort* Qs = Wb + 3 * D * D;
    ushort* Ks = Qs + R * D;
    ushort* Vt = Ks + R * D;
    ushort* Sb = Vt + R * D;   // S scores, then P in place (bf16)

    cast_bf16_all<<<dim3(11264), dim3(256), 0, stream>>>(
        x, (const float*)d_in[1], (const float*)d_in[3], (const float*)d_in[5], xb);

    // QKV: one GEMM M=8192 N=3072 K=1024; 24 N-blocks share each x-tile
    qkv_gemm<<<dim3(24, 64), dim3(256), 0, stream>>>(xb, Wb, bq, bk, bv, Qs, Ks, Vt);

    // S = Qs @ K^T per batch: M=N=2048, K=1024 (scale folded into Qs), bf16 out
    gemm_bt_bf16<<<dim3(16, 16, 4), dim3(256), 0, stream>>>(Qs, S * D, Ks, S * D, Sb, S * S,
                                                            (int)S, (int)D);

    // softmax rows in place -> bf16 P
    softmax_rows_bf16<<<dim3((unsigned)(4 * S)), dim3(256), 0, stream>>>(Sb);

    // O = P @ Vt^T per batch: M=2048, N=1024, K=2048
    gemm_bt_f32<<<dim3(8, 16, 4), dim3(256), 0, stream>>>(Sb, S * S, Vt, D * S, out, S * D,
                                                          (int)D, (int)S);
}